// Round 23
// baseline (121.308 us; speedup 1.0000x reference)
//
#include <hip/hip_runtime.h>

#define B_ 2
#define T_ 2048
#define D_ 1024
#define H_ 16
#define HD_ 64
#define NT_ (B_*T_)   // 4096

typedef __attribute__((ext_vector_type(8))) short bf16x8;
typedef __attribute__((ext_vector_type(4))) float f32x4;
typedef __attribute__((ext_vector_type(16))) float f32x16;
typedef __attribute__((ext_vector_type(4))) int i32x4;

#define MFMA32(a, b, c) __builtin_amdgcn_mfma_f32_32x32x16_bf16((a), (b), (c), 0, 0, 0)

static __device__ __forceinline__ unsigned short f2bf(float f) {
    union { float f; unsigned u; } v; v.f = f;
    unsigned r = v.u + 0x7fffu + ((v.u >> 16) & 1u);
    return (unsigned short)(r >> 16);
}

static __device__ __forceinline__ float exp2a(float x) {
    float r; asm("v_exp_f32 %0, %1" : "=v"(r) : "v"(x)); return r;
}

static __device__ __forceinline__ unsigned cvt_pk_bf16(float lo, float hi) {
    unsigned r; asm("v_cvt_pk_bf16_f32 %0, %1, %2" : "=v"(r) : "v"(lo), "v"(hi)); return r;
}

static __device__ __forceinline__ void gload_lds16(const unsigned short* g, unsigned short* l) {
    __builtin_amdgcn_global_load_lds(
        (const __attribute__((address_space(1))) unsigned int*)g,
        (__attribute__((address_space(3))) unsigned int*)l, 16, 0, 0);
}

// lgkmcnt-only barrier: does NOT drain in-flight global loads.
static __device__ __forceinline__ void lbar() {
    __builtin_amdgcn_sched_barrier(0);
    asm volatile("s_waitcnt lgkmcnt(0)" ::: "memory");
    __builtin_amdgcn_s_barrier();
    __builtin_amdgcn_sched_barrier(0);
}

// XCD-aware bijective remap (requires nwg % 8 == 0; true for all our launches).
static __device__ __forceinline__ void xcd_swz(int& bx, int& by) {
    int gx = gridDim.x, nwg = gx * gridDim.y;
    int flat = by * gx + bx;
    int cpx = nwg >> 3;
    int swz = (flat & 7) * cpx + (flat >> 3);
    bx = swz % gx; by = swz / gx;
}

// ---------------- prep: transpose+cast both weights ----------------
__global__ __launch_bounds__(256) void prep_all(
    const float* __restrict__ Wqkv, unsigned short* __restrict__ WqkvT,
    const float* __restrict__ Wout, unsigned short* __restrict__ WoutT) {
    __shared__ float tile[32][33];
    int bid = blockIdx.x, tid = threadIdx.x;
    const float* in; unsigned short* out; int R, C, bx, by;
    if (bid < 3072) {
        bx = bid % 96; by = bid / 96;
        in = Wqkv; out = WqkvT; R = 1024; C = 3072;
    } else {
        int tb = bid - 3072; bx = tb & 31; by = tb >> 5;
        in = Wout; out = WoutT; R = 1024; C = 1024;
    }
    int tx = tid & 31, ty = tid >> 5;
    int c0 = bx * 32, r0 = by * 32;
#pragma unroll
    for (int j = 0; j < 32; j += 8)
        tile[ty + j][tx] = in[(size_t)(r0 + ty + j) * C + c0 + tx];
    __syncthreads();
#pragma unroll
    for (int j = 0; j < 32; j += 8)
        out[(size_t)(c0 + ty + j) * R + r0 + tx] = f2bf(tile[tx][ty + j]);
}

// ---------------- QKV GEMM v2: 32x32 MFMA (flash-verified operand layout) ----------
// A = x (f32, cast fused), B via gload_lds, BK=64, XOR swizzle, counted-vmcnt barriers.
// Wave (wr,wc) owns a 64x64 C tile as 2x2 of 32x32; per kc (K=16): 2 A-frags + 2 B-frags
// + 4 MFMA32. C/D map: col=l31, row=(i&3)+8*(i>>2)+4*hi (m74/m101 verified).
__global__ __launch_bounds__(256) void gemm_qkv(
    const float* __restrict__ X, const unsigned short* __restrict__ Bt,
    unsigned short* __restrict__ Qo, unsigned short* __restrict__ Ko,
    unsigned short* __restrict__ Vo,
    int M, int N, int K) {
    __shared__ __align__(16) unsigned short As[128 * 64];
    __shared__ __align__(16) unsigned short Bs[128 * 64];
    int tid = threadIdx.x;
    int wv = tid >> 6, lane = tid & 63;
    int wr = wv >> 1, wc = wv & 1;
    int l31 = lane & 31, hi = lane >> 5;
    int bx = blockIdx.x, by = blockIdx.y;
    xcd_swz(bx, by);
    int tm = by * 128, tn = bx * 128;
    f32x16 acc00 = {}, acc01 = {}, acc10 = {}, acc11 = {};   // [mi][ni]

    int lrow = lane >> 3;
    int scol = ((lane & 7) ^ (lrow & 7)) * 8;   // pre-swizzled col (elements)
    int rsw = l31 & 7;                          // read-side row XOR key (row=l31 now)

    // prologue: A f32 prefetch for kt=0 (regs only)
    f32x4 apre0[4], apre1[4];
#pragma unroll
    for (int c = 0; c < 4; ++c) {
        int chunk = wv + c * 4;
        const float* ag = X + (size_t)(tm + chunk * 8 + lrow) * K + scol;
        apre0[c] = *(const f32x4*)(ag);
        apre1[c] = *(const f32x4*)(ag + 4);
    }

    for (int kt = 0; kt < K; kt += 64) {
        lbar();   // prev frag reads done (lgkm only; A-prefetch stays in flight)
#pragma unroll
        for (int c = 0; c < 4; ++c) {
            int chunk = wv + c * 4;
            i32x4 w;
            w[0] = (int)cvt_pk_bf16(apre0[c][0], apre0[c][1]);
            w[1] = (int)cvt_pk_bf16(apre0[c][2], apre0[c][3]);
            w[2] = (int)cvt_pk_bf16(apre1[c][0], apre1[c][1]);
            w[3] = (int)cvt_pk_bf16(apre1[c][2], apre1[c][3]);
            *(i32x4*)(As + chunk * 512 + lane * 8) = w;
            gload_lds16(Bt + (size_t)(tn + chunk * 8 + lrow) * K + kt + scol, Bs + chunk * 512);
        }
        __builtin_amdgcn_sched_barrier(0);   // pin: gloads issued before A-prefetch
        bool pre = (kt + 64 < K);
        if (pre) {
#pragma unroll
            for (int c = 0; c < 4; ++c) {
                int chunk = wv + c * 4;
                const float* ag = X + (size_t)(tm + chunk * 8 + lrow) * K + kt + 64 + scol;
                apre0[c] = *(const f32x4*)(ag);
                apre1[c] = *(const f32x4*)(ag + 4);
            }
        }
        __builtin_amdgcn_sched_barrier(0);   // pin: waits come after all issues
        if (pre) {
            asm volatile("s_waitcnt vmcnt(8)" ::: "memory");   // 4 gloads done; 8 A in flight
        } else {
            asm volatile("s_waitcnt vmcnt(0)" ::: "memory");
        }
        asm volatile("s_waitcnt lgkmcnt(0)" ::: "memory");     // As ds_writes done
        __builtin_amdgcn_s_barrier();
        __builtin_amdgcn_sched_barrier(0);
#pragma unroll
        for (int kc = 0; kc < 4; ++kc) {
            int slot = ((kc * 2 + hi) ^ rsw) * 8;
            bf16x8 a0 = *(const bf16x8*)(As + (wr * 64 + l31) * 64 + slot);
            bf16x8 a1 = *(const bf16x8*)(As + (wr * 64 + 32 + l31) * 64 + slot);
            bf16x8 b0 = *(const bf16x8*)(Bs + (wc * 64 + l31) * 64 + slot);
            bf16x8 b1 = *(const bf16x8*)(Bs + (wc * 64 + 32 + l31) * 64 + slot);
            acc00 = MFMA32(a0, b0, acc00);
            acc01 = MFMA32(a0, b1, acc01);
            acc10 = MFMA32(a1, b0, acc10);
            acc11 = MFMA32(a1, b1, acc11);
        }
    }

    // epilogue: scatter Q (pre-scaled) / K [bh][t][hd], V as V^T [bh][hd][t]
    const float SC = 0.125f * 1.44269504f;
#pragma unroll
    for (int mi = 0; mi < 2; ++mi) {
#pragma unroll
        for (int ni = 0; ni < 2; ++ni) {
            f32x16 accv = (mi == 0) ? ((ni == 0) ? acc00 : acc01)
                                    : ((ni == 0) ? acc10 : acc11);
            int e = tn + wc * 64 + ni * 32 + l31;
            int sec = e >> 10, rem = e & 1023;
            int h = rem >> 6, hd = rem & 63;
            int row_base = tm + wr * 64 + mi * 32;
#pragma unroll
            for (int g = 0; g < 4; ++g) {
                int tok = row_base + g * 8 + 4 * hi;   // 4 consecutive tokens tok..tok+3
                int b = tok >> 11, tl = tok & 2047;
                if (sec == 2) {   // V^T [bh][hd][t], packed u32 stores (t pairs)
                    size_t idx0 = ((size_t)(b * H_ + h) * HD_ + hd) * T_ + tl;
                    *(unsigned*)(Vo + idx0)     = cvt_pk_bf16(accv[g * 4 + 0], accv[g * 4 + 1]);
                    *(unsigned*)(Vo + idx0 + 2) = cvt_pk_bf16(accv[g * 4 + 2], accv[g * 4 + 3]);
                } else {
                    unsigned short* dst = (sec == 0) ? Qo : Ko;
                    float sc = (sec == 0) ? SC : 1.0f;
#pragma unroll
                    for (int j = 0; j < 4; ++j)
                        dst[(((size_t)(b * H_ + h) * T_ + tl + j) << 6) + hd] =
                            f2bf(accv[g * 4 + j] * sc);
                }
            }
        }
    }
}

// ---------------- out-proj GEMM: 128x64 tiles -> 512 blocks = 2/CU ----
__global__ __launch_bounds__(256) void gemm_n64(
    const unsigned short* __restrict__ A, const unsigned short* __restrict__ Bt,
    float* __restrict__ C, int M, int N, int K) {
    __shared__ __align__(16) unsigned short As[128 * 64];
    __shared__ __align__(16) unsigned short Bs[64 * 64];
    int tid = threadIdx.x;
    int wv = tid >> 6, lane = tid & 63;
    int wr = wv >> 1, wc = wv & 1;
    int l15 = lane & 15, lg = lane >> 4;
    int bx = blockIdx.x, by = blockIdx.y;
    xcd_swz(bx, by);
    int tm = by * 128, tn = bx * 64;
    f32x4 acc[4][2] = {};

    int lrow = lane >> 3;
    int scol = ((lane & 7) ^ (lrow & 7)) * 8;
    int rsw = l15 & 7;

    for (int kt = 0; kt < K; kt += 64) {
        __syncthreads();
#pragma unroll
        for (int c = 0; c < 4; ++c) {
            int chunk = wv + c * 4;
            gload_lds16(A + (size_t)(tm + chunk * 8 + lrow) * K + kt + scol, As + chunk * 512);
        }
#pragma unroll
        for (int c = 0; c < 2; ++c) {
            int chunk = wv + c * 4;
            gload_lds16(Bt + (size_t)(tn + chunk * 8 + lrow) * K + kt + scol, Bs + chunk * 512);
        }
        __syncthreads();
#pragma unroll
        for (int kk = 0; kk < 2; ++kk) {
            bf16x8 af[4], bfr[2];
#pragma unroll
            for (int m = 0; m < 4; ++m) {
                int row = wr * 64 + m * 16 + l15;
                af[m] = *(const bf16x8*)(As + row * 64 + (((kk * 4 + lg) ^ rsw) * 8));
            }
#pragma unroll
            for (int n = 0; n < 2; ++n) {
                int row = wc * 32 + n * 16 + l15;
                bfr[n] = *(const bf16x8*)(Bs + row * 64 + (((kk * 4 + lg) ^ rsw) * 8));
            }
#pragma unroll
            for (int m = 0; m < 4; ++m)
#pragma unroll
                for (int n = 0; n < 2; ++n)
                    acc[m][n] = __builtin_amdgcn_mfma_f32_16x16x32_bf16(af[m], bfr[n], acc[m][n], 0, 0, 0);
        }
    }

#pragma unroll
    for (int m = 0; m < 4; ++m) {
        int row0 = tm + wr * 64 + m * 16 + lg * 4;
#pragma unroll
        for (int n = 0; n < 2; ++n) {
            int col = tn + wc * 32 + n * 16 + l15;
#pragma unroll
            for (int r = 0; r < 4; ++r)
                C[(size_t)(row0 + r) * N + col] = acc[m][n][r];
        }
    }
}

// ---------------- flash attention v18 (verified R21/R22): lgkm-only barriers ----------
#define KPAD 72
#define VPAD 136

#define EXCH(PV, HF, FRAG)                                                     \
  do {                                                                         \
    unsigned uA0 = cvt_pk_bf16(PV[8 * HF + 0], PV[8 * HF + 1]);                \
    unsigned uA1 = cvt_pk_bf16(PV[8 * HF + 2], PV[8 * HF + 3]);                \
    unsigned uB0 = cvt_pk_bf16(PV[8 * HF + 4], PV[8 * HF + 5]);                \
    unsigned uB1 = cvt_pk_bf16(PV[8 * HF + 6], PV[8 * HF + 7]);                \
    unsigned snd0 = hi ? uA0 : uB0, snd1 = hi ? uA1 : uB1;                     \
    unsigned rc0 = (unsigned)__shfl_xor((int)snd0, 32);                        \
    unsigned rc1 = (unsigned)__shfl_xor((int)snd1, 32);                        \
    union { bf16x8 v; unsigned u[4]; } Fx;                                     \
    Fx.u[0] = hi ? rc0 : uA0;                                                  \
    Fx.u[1] = hi ? rc1 : uA1;                                                  \
    Fx.u[2] = hi ? uB0 : rc0;                                                  \
    Fx.u[3] = hi ? uB1 : rc1;                                                  \
    FRAG = Fx.v;                                                               \
  } while (0)

__global__ __launch_bounds__(256) void flash_attn(
    const unsigned short* __restrict__ Qg, const unsigned short* __restrict__ Kg,
    const unsigned short* __restrict__ VTg, const int* __restrict__ mask,
    unsigned short* __restrict__ AO) {
    __shared__ __align__(16) unsigned short Ks[128 * KPAD];
    __shared__ __align__(16) unsigned short VTs[64 * VPAD];
    __shared__ float biasS[128];

    int tid = threadIdx.x, wv = tid >> 6, lane = tid & 63;
    int l31 = lane & 31, hi = lane >> 5;
    int bx = blockIdx.x, by = blockIdx.y;
    xcd_swz(bx, by);
    int bh = by;
    int b = bh >> 4, h = bh & 15;
    int q0 = bx * 128;
    const unsigned short* Qb  = Qg  + (size_t)bh * T_ * HD_;
    const unsigned short* Kb  = Kg  + (size_t)bh * T_ * HD_;
    const unsigned short* VTb = VTg + (size_t)bh * HD_ * T_;

    bf16x8 qf[4];
    {
        const unsigned short* qrow = Qb + (size_t)(q0 + wv * 32 + l31) * HD_;
#pragma unroll
        for (int c = 0; c < 4; ++c)
            qf[c] = *(const bf16x8*)(qrow + c * 16 + hi * 8);
    }

    float lp0 = 0.f, lp1 = 0.f, lp2 = 0.f, lp3 = 0.f;
    f32x16 o0 = {}, o1 = {};

    i32x4 kv[4], vvv[4];
#pragma unroll
    for (int c = 0; c < 4; ++c) {
        int idx = tid + c * 256;
        kv[c]  = *(const i32x4*)(Kb + (size_t)(idx >> 3) * HD_ + (idx & 7) * 8);
        vvv[c] = *(const i32x4*)(VTb + (size_t)(idx >> 4) * T_ + (idx & 15) * 8);
    }
    int mA = mask[b * T_ + lane];
    int mB = mask[b * T_ + 64 + lane];

    for (int kt = 0; kt < T_; kt += 128) {
        bool nomask = __all(mA != 0 && mB != 0);
        lbar();
#pragma unroll
        for (int c = 0; c < 4; ++c) {
            int idx = tid + c * 256;
            *(i32x4*)(Ks + (idx >> 3) * KPAD + (idx & 7) * 8) = kv[c];
            *(i32x4*)(VTs + (idx >> 4) * VPAD + (idx & 15) * 8) = vvv[c];
        }
        if (!nomask && wv == 0) {
            biasS[lane]      = mA ? 0.f : -1e30f;
            biasS[64 + lane] = mB ? 0.f : -1e30f;
        }
        if (kt + 128 < T_) {
#pragma unroll
            for (int c = 0; c < 4; ++c) {
                int idx = tid + c * 256;
                kv[c]  = *(const i32x4*)(Kb + (size_t)(kt + 128 + (idx >> 3)) * HD_ + (idx & 7) * 8);
                vvv[c] = *(const i32x4*)(VTb + (size_t)(idx >> 4) * T_ + kt + 128 + (idx & 15) * 8);
            }
            mA = mask[b * T_ + kt + 128 + lane];
            mB = mask[b * T_ + kt + 192 + lane];
        }
        lbar();

#pragma unroll
        for (int hp = 0; hp < 2; ++hp) {
            f32x16 s0 = {}, s1 = {};
            __builtin_amdgcn_s_setprio(1);
#pragma unroll
            for (int c = 0; c < 4; ++c) {
                bf16x8 ka = *(const bf16x8*)(Ks + ((hp * 2 + 0) * 32 + l31) * KPAD + c * 16 + hi * 8);
                s0 = MFMA32(ka, qf[c], s0);
            }
#pragma unroll
            for (int c = 0; c < 4; ++c) {
                bf16x8 kb2 = *(const bf16x8*)(Ks + ((hp * 2 + 1) * 32 + l31) * KPAD + c * 16 + hi * 8);
                s1 = MFMA32(kb2, qf[c], s1);
            }
            __builtin_amdgcn_s_setprio(0);

            if (!nomask) {
#pragma unroll
                for (int i = 0; i < 16; ++i) {
                    int krow = (i & 3) + 8 * (i >> 2) + 4 * hi;
                    s0[i] += biasS[hp * 64 + krow];
                    s1[i] += biasS[hp * 64 + 32 + krow];
                }
            }
#pragma unroll
            for (int i = 0; i < 16; i += 4) {
                s0[i] = exp2a(s0[i]);     s0[i+1] = exp2a(s0[i+1]);
                s0[i+2] = exp2a(s0[i+2]); s0[i+3] = exp2a(s0[i+3]);
                s1[i] = exp2a(s1[i]);     s1[i+1] = exp2a(s1[i+1]);
                s1[i+2] = exp2a(s1[i+2]); s1[i+3] = exp2a(s1[i+3]);
                lp0 += s0[i]   + s1[i];
                lp1 += s0[i+1] + s1[i+1];
                lp2 += s0[i+2] + s1[i+2];
                lp3 += s0[i+3] + s1[i+3];
            }
            bf16x8 fr0, fr1, fr2, fr3;
            EXCH(s0, 0, fr0);
            EXCH(s0, 1, fr1);
            EXCH(s1, 0, fr2);
            EXCH(s1, 1, fr3);

            __builtin_amdgcn_s_setprio(1);
#pragma unroll
            for (int kc = 0; kc < 4; ++kc) {
                bf16x8 fr = (kc == 0) ? fr0 : (kc == 1) ? fr1 : (kc == 2) ? fr2 : fr3;
                bf16x8 va = *(const bf16x8*)(VTs + l31 * VPAD + hp * 64 + kc * 16 + hi * 8);
                bf16x8 vb = *(const bf16x8*)(VTs + (32 + l31) * VPAD + hp * 64 + kc * 16 + hi * 8);
                o0 = MFMA32(fr, va, o0);
                o1 = MFMA32(fr, vb, o1);
            }
            __builtin_amdgcn_s_setprio(0);
        }
    }

    float l_part = (lp0 + lp1) + (lp2 + lp3);
    l_part += __shfl_xor(l_part, 32);

    size_t rowD = (size_t)(b * T_ + q0 + wv * 32) * D_ + h * 64;
#pragma unroll
    for (int i = 0; i < 16; ++i) {
        int qrow = (i & 3) + 8 * (i >> 2) + 4 * hi;
        float lq = __shfl(l_part, qrow);
        float inv = 1.0f / lq;
        AO[rowD + (size_t)qrow * D_ + l31]      = f2bf(o0[i] * inv);
        AO[rowD + (size_t)qrow * D_ + 32 + l31] = f2bf(o1[i] * inv);
    }
}

extern "C" void kernel_launch(void* const* d_in, const int* in_sizes, int n_in,
                              void* d_out, int out_size, void* d_ws, size_t ws_size,
                              hipStream_t stream) {
    const float* x    = (const float*)d_in[0];
    const int*   mask = (const int*)d_in[1];
    const float* Wqkv = (const float*)d_in[2];
    const float* Wout = (const float*)d_in[3];
    float* out = (float*)d_out;
    char* ws = (char*)d_ws;

    unsigned short* AO    = (unsigned short*)(ws);                       // 8 MB
    unsigned short* WqkvT = (unsigned short*)(ws + (size_t)(8u << 20));  // 6 MB
    unsigned short* WoutT = (unsigned short*)(ws + (size_t)(14u << 20)); // 2 MB
    unsigned short* Qg    = (unsigned short*)(ws + (size_t)(16u << 20)); // 8 MB
    unsigned short* Kg    = (unsigned short*)(ws + (size_t)(24u << 20)); // 8 MB
    unsigned short* VT    = (unsigned short*)(ws + (size_t)(32u << 20)); // 8 MB (V transposed)

    prep_all<<<4096, 256, 0, stream>>>(Wqkv, WqkvT, Wout, WoutT);
    gemm_qkv<<<dim3(3072 / 128, 4096 / 128), 256, 0, stream>>>(
        x, WqkvT, Qg, Kg, VT, NT_, 3 * D_, D_);
    flash_attn<<<dim3(T_ / 128, B_ * H_), 256, 0, stream>>>(Qg, Kg, VT, mask, AO);
    gemm_n64<<<dim3(1024 / 64, 4096 / 128), 256, 0, stream>>>(
        AO, WoutT, out, NT_, D_, D_);
}

// Round 24
// 117.541 us; speedup vs baseline: 1.0321x; 1.0321x over previous
//
#include <hip/hip_runtime.h>

#define B_ 2
#define T_ 2048
#define D_ 1024
#define H_ 16
#define HD_ 64
#define NT_ (B_*T_)   // 4096

typedef __attribute__((ext_vector_type(8))) short bf16x8;
typedef __attribute__((ext_vector_type(4))) float f32x4;
typedef __attribute__((ext_vector_type(16))) float f32x16;
typedef __attribute__((ext_vector_type(4))) int i32x4;

#define MFMA32(a, b, c) __builtin_amdgcn_mfma_f32_32x32x16_bf16((a), (b), (c), 0, 0, 0)

static __device__ __forceinline__ unsigned short f2bf(float f) {
    union { float f; unsigned u; } v; v.f = f;
    unsigned r = v.u + 0x7fffu + ((v.u >> 16) & 1u);
    return (unsigned short)(r >> 16);
}

static __device__ __forceinline__ float exp2a(float x) {
    float r; asm("v_exp_f32 %0, %1" : "=v"(r) : "v"(x)); return r;
}

static __device__ __forceinline__ unsigned cvt_pk_bf16(float lo, float hi) {
    unsigned r; asm("v_cvt_pk_bf16_f32 %0, %1, %2" : "=v"(r) : "v"(lo), "v"(hi)); return r;
}

static __device__ __forceinline__ void gload_lds16(const unsigned short* g, unsigned short* l) {
    __builtin_amdgcn_global_load_lds(
        (const __attribute__((address_space(1))) unsigned int*)g,
        (__attribute__((address_space(3))) unsigned int*)l, 16, 0, 0);
}

// lgkmcnt-only barrier: does NOT drain in-flight global loads.
static __device__ __forceinline__ void lbar() {
    __builtin_amdgcn_sched_barrier(0);
    asm volatile("s_waitcnt lgkmcnt(0)" ::: "memory");
    __builtin_amdgcn_s_barrier();
    __builtin_amdgcn_sched_barrier(0);
}

// XCD-aware bijective remap (requires nwg % 8 == 0; true for all our launches).
static __device__ __forceinline__ void xcd_swz(int& bx, int& by) {
    int gx = gridDim.x, nwg = gx * gridDim.y;
    int flat = by * gx + bx;
    int cpx = nwg >> 3;
    int swz = (flat & 7) * cpx + (flat >> 3);
    bx = swz % gx; by = swz / gx;
}

// ---------------- prep: transpose+cast Wqkv only (Wout rides in gemm_qkv dispatch) ------
__global__ __launch_bounds__(256) void prep_all(
    const float* __restrict__ Wqkv, unsigned short* __restrict__ WqkvT) {
    __shared__ float tile[32][33];
    int bid = blockIdx.x, tid = threadIdx.x;
    int bx = bid % 96, by = bid / 96;
    const int R = 1024, C = 3072;
    int tx = tid & 31, ty = tid >> 5;
    int c0 = bx * 32, r0 = by * 32;
#pragma unroll
    for (int j = 0; j < 32; j += 8)
        tile[ty + j][tx] = Wqkv[(size_t)(r0 + ty + j) * C + c0 + tx];
    __syncthreads();
#pragma unroll
    for (int j = 0; j < 32; j += 8)
        WqkvT[(size_t)(c0 + ty + j) * R + r0 + tx] = f2bf(tile[tx][ty + j]);
}

// ---------------- QKV GEMM (verified R22 16x16 version) + embedded Wout transpose ------
// Blocks [0,768): GEMM (flat-swizzled). Blocks [768,1792): Wout 32x32 transpose tiles.
__global__ __launch_bounds__(256) void gemm_qkv(
    const float* __restrict__ X, const unsigned short* __restrict__ Bt,
    unsigned short* __restrict__ Qo, unsigned short* __restrict__ Ko,
    unsigned short* __restrict__ Vo,
    const float* __restrict__ Wout, unsigned short* __restrict__ WoutT,
    int M, int N, int K) {
    __shared__ __align__(16) unsigned short As[128 * 64];
    __shared__ __align__(16) unsigned short Bs[128 * 64];
    int tid = threadIdx.x;

    if (blockIdx.x >= 768) {   // Wout transpose tile (independent of WqkvT)
        float* tile = (float*)As;   // 33*32*4 B scratch overlay
        int tb = blockIdx.x - 768;
        int tbx = tb & 31, tby = tb >> 5;
        int tx = tid & 31, ty = tid >> 5;
        int c0 = tbx * 32, r0 = tby * 32;
#pragma unroll
        for (int j = 0; j < 32; j += 8)
            tile[(ty + j) * 33 + tx] = Wout[(size_t)(r0 + ty + j) * 1024 + c0 + tx];
        __syncthreads();
#pragma unroll
        for (int j = 0; j < 32; j += 8)
            WoutT[(size_t)(c0 + ty + j) * 1024 + r0 + tx] = f2bf(tile[tx * 33 + ty + j]);
        return;
    }

    int wv = tid >> 6, lane = tid & 63;
    int wr = wv >> 1, wc = wv & 1;
    int l15 = lane & 15, lg = lane >> 4;
    int flat = blockIdx.x;
    int swz = (flat & 7) * 96 + (flat >> 3);   // bijective over 768
    int bx = swz % 24, by = swz / 24;
    int tm = by * 128, tn = bx * 128;
    f32x4 acc[4][4] = {};

    int lrow = lane >> 3;
    int scol = ((lane & 7) ^ (lrow & 7)) * 8;   // pre-swizzled col (elements)
    int rsw = l15 & 7;

    // prologue: A f32 prefetch for kt=0 (regs only)
    f32x4 apre0[4], apre1[4];
#pragma unroll
    for (int c = 0; c < 4; ++c) {
        int chunk = wv + c * 4;
        const float* ag = X + (size_t)(tm + chunk * 8 + lrow) * K + scol;
        apre0[c] = *(const f32x4*)(ag);
        apre1[c] = *(const f32x4*)(ag + 4);
    }

    for (int kt = 0; kt < K; kt += 64) {
        lbar();   // prev frag reads done (lgkm only; A-prefetch stays in flight)
#pragma unroll
        for (int c = 0; c < 4; ++c) {
            int chunk = wv + c * 4;
            i32x4 w;
            w[0] = (int)cvt_pk_bf16(apre0[c][0], apre0[c][1]);
            w[1] = (int)cvt_pk_bf16(apre0[c][2], apre0[c][3]);
            w[2] = (int)cvt_pk_bf16(apre1[c][0], apre1[c][1]);
            w[3] = (int)cvt_pk_bf16(apre1[c][2], apre1[c][3]);
            *(i32x4*)(As + chunk * 512 + lane * 8) = w;
            gload_lds16(Bt + (size_t)(tn + chunk * 8 + lrow) * K + kt + scol, Bs + chunk * 512);
        }
        __builtin_amdgcn_sched_barrier(0);   // pin: gloads issued before A-prefetch
        bool pre = (kt + 64 < K);
        if (pre) {
#pragma unroll
            for (int c = 0; c < 4; ++c) {
                int chunk = wv + c * 4;
                const float* ag = X + (size_t)(tm + chunk * 8 + lrow) * K + kt + 64 + scol;
                apre0[c] = *(const f32x4*)(ag);
                apre1[c] = *(const f32x4*)(ag + 4);
            }
        }
        __builtin_amdgcn_sched_barrier(0);   // pin: waits come after all issues
        if (pre) {
            asm volatile("s_waitcnt vmcnt(8)" ::: "memory");   // 4 gloads done; 8 A in flight
        } else {
            asm volatile("s_waitcnt vmcnt(0)" ::: "memory");
        }
        asm volatile("s_waitcnt lgkmcnt(0)" ::: "memory");     // As ds_writes done
        __builtin_amdgcn_s_barrier();
        __builtin_amdgcn_sched_barrier(0);
#pragma unroll
        for (int kk = 0; kk < 2; ++kk) {
            bf16x8 af[4], bfr[4];
#pragma unroll
            for (int m = 0; m < 4; ++m) {
                int row = wr * 64 + m * 16 + l15;
                af[m] = *(const bf16x8*)(As + row * 64 + (((kk * 4 + lg) ^ rsw) * 8));
            }
#pragma unroll
            for (int n = 0; n < 4; ++n) {
                int row = wc * 64 + n * 16 + l15;
                bfr[n] = *(const bf16x8*)(Bs + row * 64 + (((kk * 4 + lg) ^ rsw) * 8));
            }
#pragma unroll
            for (int m = 0; m < 4; ++m)
#pragma unroll
                for (int n = 0; n < 4; ++n)
                    acc[m][n] = __builtin_amdgcn_mfma_f32_16x16x32_bf16(af[m], bfr[n], acc[m][n], 0, 0, 0);
        }
    }

    const float SC = 0.125f * 1.44269504f;   // folded into Q
#pragma unroll
    for (int m = 0; m < 4; ++m) {
        int row0 = tm + wr * 64 + m * 16 + lg * 4;
#pragma unroll
        for (int n = 0; n < 4; ++n) {
            int e = tn + wc * 64 + n * 16 + l15;
            int sec = e >> 10, rem = e & 1023;
            int h = rem >> 6, hd = rem & 63;
            int tok = row0;
            int b = tok >> 11, tl = tok & 2047;
            if (sec == 2) {   // V^T [bh][hd][t], packed u32 stores
                size_t idx0 = ((size_t)(b * H_ + h) * HD_ + hd) * T_ + tl;
                *(unsigned*)(Vo + idx0)     = cvt_pk_bf16(acc[m][n][0], acc[m][n][1]);
                *(unsigned*)(Vo + idx0 + 2) = cvt_pk_bf16(acc[m][n][2], acc[m][n][3]);
            } else {
                unsigned short* dst = (sec == 0) ? Qo : Ko;
                float sc = (sec == 0) ? SC : 1.0f;
#pragma unroll
                for (int r = 0; r < 4; ++r)
                    dst[(((size_t)(b * H_ + h) * T_ + tl + r) << 6) + hd] =
                        f2bf(acc[m][n][r] * sc);
            }
        }
    }
}

// ---------------- out-proj GEMM: 128x64 tiles -> 512 blocks = 2/CU ----
__global__ __launch_bounds__(256) void gemm_n64(
    const unsigned short* __restrict__ A, const unsigned short* __restrict__ Bt,
    float* __restrict__ C, int M, int N, int K) {
    __shared__ __align__(16) unsigned short As[128 * 64];
    __shared__ __align__(16) unsigned short Bs[64 * 64];
    int tid = threadIdx.x;
    int wv = tid >> 6, lane = tid & 63;
    int wr = wv >> 1, wc = wv & 1;
    int l15 = lane & 15, lg = lane >> 4;
    int bx = blockIdx.x, by = blockIdx.y;
    xcd_swz(bx, by);
    int tm = by * 128, tn = bx * 64;
    f32x4 acc[4][2] = {};

    int lrow = lane >> 3;
    int scol = ((lane & 7) ^ (lrow & 7)) * 8;
    int rsw = l15 & 7;

    for (int kt = 0; kt < K; kt += 64) {
        __syncthreads();
#pragma unroll
        for (int c = 0; c < 4; ++c) {
            int chunk = wv + c * 4;
            gload_lds16(A + (size_t)(tm + chunk * 8 + lrow) * K + kt + scol, As + chunk * 512);
        }
#pragma unroll
        for (int c = 0; c < 2; ++c) {
            int chunk = wv + c * 4;
            gload_lds16(Bt + (size_t)(tn + chunk * 8 + lrow) * K + kt + scol, Bs + chunk * 512);
        }
        __syncthreads();
#pragma unroll
        for (int kk = 0; kk < 2; ++kk) {
            bf16x8 af[4], bfr[2];
#pragma unroll
            for (int m = 0; m < 4; ++m) {
                int row = wr * 64 + m * 16 + l15;
                af[m] = *(const bf16x8*)(As + row * 64 + (((kk * 4 + lg) ^ rsw) * 8));
            }
#pragma unroll
            for (int n = 0; n < 2; ++n) {
                int row = wc * 32 + n * 16 + l15;
                bfr[n] = *(const bf16x8*)(Bs + row * 64 + (((kk * 4 + lg) ^ rsw) * 8));
            }
#pragma unroll
            for (int m = 0; m < 4; ++m)
#pragma unroll
                for (int n = 0; n < 2; ++n)
                    acc[m][n] = __builtin_amdgcn_mfma_f32_16x16x32_bf16(af[m], bfr[n], acc[m][n], 0, 0, 0);
        }
    }

#pragma unroll
    for (int m = 0; m < 4; ++m) {
        int row0 = tm + wr * 64 + m * 16 + lg * 4;
#pragma unroll
        for (int n = 0; n < 2; ++n) {
            int col = tn + wc * 32 + n * 16 + l15;
#pragma unroll
            for (int r = 0; r < 4; ++r)
                C[(size_t)(row0 + r) * N + col] = acc[m][n][r];
        }
    }
}

// ---------------- flash attention v18 (verified R21/R22): lgkm-only barriers ----------
#define KPAD 72
#define VPAD 136

#define EXCH(PV, HF, FRAG)                                                     \
  do {                                                                         \
    unsigned uA0 = cvt_pk_bf16(PV[8 * HF + 0], PV[8 * HF + 1]);                \
    unsigned uA1 = cvt_pk_bf16(PV[8 * HF + 2], PV[8 * HF + 3]);                \
    unsigned uB0 = cvt_pk_bf16(PV[8 * HF + 4], PV[8 * HF + 5]);                \
    unsigned uB1 = cvt_pk_bf16(PV[8 * HF + 6], PV[8 * HF + 7]);                \
    unsigned snd0 = hi ? uA0 : uB0, snd1 = hi ? uA1 : uB1;                     \
    unsigned rc0 = (unsigned)__shfl_xor((int)snd0, 32);                        \
    unsigned rc1 = (unsigned)__shfl_xor((int)snd1, 32);                        \
    union { bf16x8 v; unsigned u[4]; } Fx;                                     \
    Fx.u[0] = hi ? rc0 : uA0;                                                  \
    Fx.u[1] = hi ? rc1 : uA1;                                                  \
    Fx.u[2] = hi ? uB0 : rc0;                                                  \
    Fx.u[3] = hi ? uB1 : rc1;                                                  \
    FRAG = Fx.v;                                                               \
  } while (0)

__global__ __launch_bounds__(256) void flash_attn(
    const unsigned short* __restrict__ Qg, const unsigned short* __restrict__ Kg,
    const unsigned short* __restrict__ VTg, const int* __restrict__ mask,
    unsigned short* __restrict__ AO) {
    __shared__ __align__(16) unsigned short Ks[128 * KPAD];
    __shared__ __align__(16) unsigned short VTs[64 * VPAD];
    __shared__ float biasS[128];

    int tid = threadIdx.x, wv = tid >> 6, lane = tid & 63;
    int l31 = lane & 31, hi = lane >> 5;
    int bx = blockIdx.x, by = blockIdx.y;
    xcd_swz(bx, by);
    int bh = by;
    int b = bh >> 4, h = bh & 15;
    int q0 = bx * 128;
    const unsigned short* Qb  = Qg  + (size_t)bh * T_ * HD_;
    const unsigned short* Kb  = Kg  + (size_t)bh * T_ * HD_;
    const unsigned short* VTb = VTg + (size_t)bh * HD_ * T_;

    bf16x8 qf[4];
    {
        const unsigned short* qrow = Qb + (size_t)(q0 + wv * 32 + l31) * HD_;
#pragma unroll
        for (int c = 0; c < 4; ++c)
            qf[c] = *(const bf16x8*)(qrow + c * 16 + hi * 8);
    }

    float lp0 = 0.f, lp1 = 0.f, lp2 = 0.f, lp3 = 0.f;
    f32x16 o0 = {}, o1 = {};

    i32x4 kv[4], vvv[4];
#pragma unroll
    for (int c = 0; c < 4; ++c) {
        int idx = tid + c * 256;
        kv[c]  = *(const i32x4*)(Kb + (size_t)(idx >> 3) * HD_ + (idx & 7) * 8);
        vvv[c] = *(const i32x4*)(VTb + (size_t)(idx >> 4) * T_ + (idx & 15) * 8);
    }
    int mA = mask[b * T_ + lane];
    int mB = mask[b * T_ + 64 + lane];

    for (int kt = 0; kt < T_; kt += 128) {
        bool nomask = __all(mA != 0 && mB != 0);
        lbar();
#pragma unroll
        for (int c = 0; c < 4; ++c) {
            int idx = tid + c * 256;
            *(i32x4*)(Ks + (idx >> 3) * KPAD + (idx & 7) * 8) = kv[c];
            *(i32x4*)(VTs + (idx >> 4) * VPAD + (idx & 15) * 8) = vvv[c];
        }
        if (!nomask && wv == 0) {
            biasS[lane]      = mA ? 0.f : -1e30f;
            biasS[64 + lane] = mB ? 0.f : -1e30f;
        }
        if (kt + 128 < T_) {
#pragma unroll
            for (int c = 0; c < 4; ++c) {
                int idx = tid + c * 256;
                kv[c]  = *(const i32x4*)(Kb + (size_t)(kt + 128 + (idx >> 3)) * HD_ + (idx & 7) * 8);
                vvv[c] = *(const i32x4*)(VTb + (size_t)(idx >> 4) * T_ + kt + 128 + (idx & 15) * 8);
            }
            mA = mask[b * T_ + kt + 128 + lane];
            mB = mask[b * T_ + kt + 192 + lane];
        }
        lbar();

#pragma unroll
        for (int hp = 0; hp < 2; ++hp) {
            f32x16 s0 = {}, s1 = {};
            __builtin_amdgcn_s_setprio(1);
#pragma unroll
            for (int c = 0; c < 4; ++c) {
                bf16x8 ka = *(const bf16x8*)(Ks + ((hp * 2 + 0) * 32 + l31) * KPAD + c * 16 + hi * 8);
                s0 = MFMA32(ka, qf[c], s0);
            }
#pragma unroll
            for (int c = 0; c < 4; ++c) {
                bf16x8 kb2 = *(const bf16x8*)(Ks + ((hp * 2 + 1) * 32 + l31) * KPAD + c * 16 + hi * 8);
                s1 = MFMA32(kb2, qf[c], s1);
            }
            __builtin_amdgcn_s_setprio(0);

            if (!nomask) {
#pragma unroll
                for (int i = 0; i < 16; ++i) {
                    int krow = (i & 3) + 8 * (i >> 2) + 4 * hi;
                    s0[i] += biasS[hp * 64 + krow];
                    s1[i] += biasS[hp * 64 + 32 + krow];
                }
            }
#pragma unroll
            for (int i = 0; i < 16; i += 4) {
                s0[i] = exp2a(s0[i]);     s0[i+1] = exp2a(s0[i+1]);
                s0[i+2] = exp2a(s0[i+2]); s0[i+3] = exp2a(s0[i+3]);
                s1[i] = exp2a(s1[i]);     s1[i+1] = exp2a(s1[i+1]);
                s1[i+2] = exp2a(s1[i+2]); s1[i+3] = exp2a(s1[i+3]);
                lp0 += s0[i]   + s1[i];
                lp1 += s0[i+1] + s1[i+1];
                lp2 += s0[i+2] + s1[i+2];
                lp3 += s0[i+3] + s1[i+3];
            }
            bf16x8 fr0, fr1, fr2, fr3;
            EXCH(s0, 0, fr0);
            EXCH(s0, 1, fr1);
            EXCH(s1, 0, fr2);
            EXCH(s1, 1, fr3);

            __builtin_amdgcn_s_setprio(1);
#pragma unroll
            for (int kc = 0; kc < 4; ++kc) {
                bf16x8 fr = (kc == 0) ? fr0 : (kc == 1) ? fr1 : (kc == 2) ? fr2 : fr3;
                bf16x8 va = *(const bf16x8*)(VTs + l31 * VPAD + hp * 64 + kc * 16 + hi * 8);
                bf16x8 vb = *(const bf16x8*)(VTs + (32 + l31) * VPAD + hp * 64 + kc * 16 + hi * 8);
                o0 = MFMA32(fr, va, o0);
                o1 = MFMA32(fr, vb, o1);
            }
            __builtin_amdgcn_s_setprio(0);
        }
    }

    float l_part = (lp0 + lp1) + (lp2 + lp3);
    l_part += __shfl_xor(l_part, 32);

    size_t rowD = (size_t)(b * T_ + q0 + wv * 32) * D_ + h * 64;
#pragma unroll
    for (int i = 0; i < 16; ++i) {
        int qrow = (i & 3) + 8 * (i >> 2) + 4 * hi;
        float lq = __shfl(l_part, qrow);
        float inv = 1.0f / lq;
        AO[rowD + (size_t)qrow * D_ + l31]      = f2bf(o0[i] * inv);
        AO[rowD + (size_t)qrow * D_ + 32 + l31] = f2bf(o1[i] * inv);
    }
}

extern "C" void kernel_launch(void* const* d_in, const int* in_sizes, int n_in,
                              void* d_out, int out_size, void* d_ws, size_t ws_size,
                              hipStream_t stream) {
    const float* x    = (const float*)d_in[0];
    const int*   mask = (const int*)d_in[1];
    const float* Wqkv = (const float*)d_in[2];
    const float* Wout = (const float*)d_in[3];
    float* out = (float*)d_out;
    char* ws = (char*)d_ws;

    unsigned short* AO    = (unsigned short*)(ws);                       // 8 MB
    unsigned short* WqkvT = (unsigned short*)(ws + (size_t)(8u << 20));  // 6 MB
    unsigned short* WoutT = (unsigned short*)(ws + (size_t)(14u << 20)); // 2 MB
    unsigned short* Qg    = (unsigned short*)(ws + (size_t)(16u << 20)); // 8 MB
    unsigned short* Kg    = (unsigned short*)(ws + (size_t)(24u << 20)); // 8 MB
    unsigned short* VT    = (unsigned short*)(ws + (size_t)(32u << 20)); // 8 MB (V transposed)

    prep_all<<<3072, 256, 0, stream>>>(Wqkv, WqkvT);
    gemm_qkv<<<1792, 256, 0, stream>>>(
        x, WqkvT, Qg, Kg, VT, Wout, WoutT, NT_, 3 * D_, D_);
    flash_attn<<<dim3(T_ / 128, B_ * H_), 256, 0, stream>>>(Qg, Kg, VT, mask, AO);
    gemm_n64<<<dim3(1024 / 64, 4096 / 128), 256, 0, stream>>>(
        AO, WoutT, out, NT_, D_, D_);
}